// Round 1
// baseline (353.432 us; speedup 1.0000x reference)
//
#include <hip/hip_runtime.h>

constexpr int N = 50000;    // nodes
constexpr int E = 800000;   // edges
constexpr int NPAD = 50048; // padded to 64-row multiple for GEMM A tiles
constexpr int NB = (N + 255) / 256;   // 196 scan blocks

typedef _Float16 half8 __attribute__((ext_vector_type(8)));
typedef _Float16 half4v __attribute__((ext_vector_type(4)));
typedef float float4v __attribute__((ext_vector_type(4)));

// ---------------- degree / normalization / CSR ----------------
__global__ __launch_bounds__(256) void deg_kernel(const int* __restrict__ dst,
                                                  int* __restrict__ degI) {
    int e = blockIdx.x * 256 + threadIdx.x;
    if (e < E) atomicAdd(&degI[dst[e]], 1);
}

__global__ __launch_bounds__(256) void dinv_kernel(const int* __restrict__ degI,
                                                   float* __restrict__ dinv) {
    int v = blockIdx.x * 256 + threadIdx.x;
    if (v < N) dinv[v] = rsqrtf((float)degI[v] + 1.0f);   // +1 = self loop
}

// ---- 3-phase scan ----
__global__ __launch_bounds__(256) void scan1_kernel(const int* __restrict__ degI,
                                                    int* __restrict__ incl,
                                                    int* __restrict__ blockSums) {
    __shared__ int s[256];
    int t = threadIdx.x;
    int i = blockIdx.x * 256 + t;
    int d = (i < N) ? degI[i] : 0;
    s[t] = d;
    __syncthreads();
    for (int off = 1; off < 256; off <<= 1) {
        int v = s[t];
        int u = (t >= off) ? s[t - off] : 0;
        __syncthreads();
        s[t] = v + u;
        __syncthreads();
    }
    if (i < N) incl[i] = s[t];
    if (t == 255) blockSums[blockIdx.x] = s[255];
}

__global__ __launch_bounds__(256) void scan2_kernel(int* __restrict__ blockSums) {
    __shared__ int s[256];
    int t = threadIdx.x;
    int v = (t < NB) ? blockSums[t] : 0;
    s[t] = v;
    __syncthreads();
    for (int off = 1; off < 256; off <<= 1) {
        int a = s[t];
        int u = (t >= off) ? s[t - off] : 0;
        __syncthreads();
        s[t] = a + u;
        __syncthreads();
    }
    if (t < NB) blockSums[t] = s[t] - v;   // exclusive block offset
}

__global__ __launch_bounds__(256) void scan3_kernel(const int* __restrict__ degI,
                                                    const int* __restrict__ incl,
                                                    const int* __restrict__ blockSums,
                                                    int* __restrict__ rowptr,
                                                    int* __restrict__ cursor) {
    int i = blockIdx.x * 256 + threadIdx.x;
    if (i < N) {
        int e = blockSums[blockIdx.x] + incl[i] - degI[i];
        rowptr[i] = e;
        cursor[i] = e;
    }
    if (i == 0) rowptr[N] = E;
}

__global__ __launch_bounds__(256) void fill_kernel(const int* __restrict__ src,
                                                   const int* __restrict__ dst,
                                                   int* __restrict__ cursor,
                                                   int* __restrict__ eidx) {
    int e = blockIdx.x * 256 + threadIdx.x;
    if (e >= E) return;
    int d = dst[e];
    int pos = atomicAdd(&cursor[d], 1);
    eidx[pos] = src[e];
}

// ---------------- weight transpose+cast: Wt[n][k] = (f16) W[k][n] ----------------
template <int K>
__global__ __launch_bounds__(256) void wt_kernel(const float* __restrict__ W,
                                                 _Float16* __restrict__ Wt) {
    int idx = blockIdx.x * 256 + threadIdx.x;
    int k = idx & (K - 1);
    int n = idx >> (K == 128 ? 7 : 8);
    Wt[idx] = (_Float16)W[(size_t)k * 256 + n];
}

// ---------------- prescale: px = dinv[v] * x   (fp32 -> fp16, 128 ch) ----------------
__global__ __launch_bounds__(256) void prescale_kernel(const float4* __restrict__ x,
                                                       const float* __restrict__ dinv,
                                                       half4v* __restrict__ px) {
    int idx = blockIdx.x * 256 + threadIdx.x;
    if (idx >= N * 32) return;
    float dv = dinv[idx >> 5];
    float4 t = x[idx];
    half4v o;
    o[0] = (_Float16)(t.x * dv);
    o[1] = (_Float16)(t.y * dv);
    o[2] = (_Float16)(t.z * dv);
    o[3] = (_Float16)(t.w * dv);
    px[idx] = o;
}

// ---------------- XCD-chunked gather-aggregate ----------------
// Channel-chunk the gather so each XCD (blockIdx%8 under round-robin dispatch)
// only reads a 64 B (32-ch f16) column slice of the table: working set
// N*64B = 3.2 MB < 4 MiB per-XCD L2 -> gathers become L2 hits after first touch.
// T = total channels. T=256: 8 chunks, 1 node segment. T=128: 4 chunks x 2 segments.
// Layout per block: 8 lanes per node (8 x 8 B = one 64 B line per edge read),
// 32 nodes per 256-thread block. f32 accumulation, final *dinv[v], f16 store.
template <int T>
__global__ __launch_bounds__(256) void aggregate_chunked(
    const int* __restrict__ rowptr, const int* __restrict__ eidx,
    const half4v* __restrict__ f, const float* __restrict__ dinv,
    half4v* __restrict__ q) {
    constexpr int NCHUNK = T / 32;      // 32-ch chunks per row (4 or 8)
    constexpr int NSEG = 8 / NCHUNK;    // node segments (2 or 1)
    constexpr int SEGN = N / NSEG;      // nodes per segment (N divisible)
    constexpr int RS = T / 4;           // row stride in half4v units

    const int slot = blockIdx.x & 7;           // -> XCD under round-robin
    const int chunk = slot & (NCHUNK - 1);
    const int seg = slot / NCHUNK;
    const int sub = threadIdx.x >> 3;          // 32 nodes per block
    const int cl = threadIdx.x & 7;            // 8 lanes x 8 B = 64 B chunk
    const int v = seg * SEGN + (blockIdx.x >> 3) * 32 + sub;
    if (v >= seg * SEGN + SEGN) return;

    const int coff = chunk * 8 + cl;

    // self loop contribution
    half4v s = f[(size_t)v * RS + coff];
    float a0 = (float)s[0], a1 = (float)s[1], a2 = (float)s[2], a3 = (float)s[3];

    int i = rowptr[v];
    const int end = rowptr[v + 1];
    for (; i + 4 <= end; i += 4) {
        int e0 = eidx[i + 0], e1 = eidx[i + 1], e2 = eidx[i + 2], e3 = eidx[i + 3];
        half4v t0 = f[(size_t)e0 * RS + coff];
        half4v t1 = f[(size_t)e1 * RS + coff];
        half4v t2 = f[(size_t)e2 * RS + coff];
        half4v t3 = f[(size_t)e3 * RS + coff];
        a0 += ((float)t0[0] + (float)t1[0]) + ((float)t2[0] + (float)t3[0]);
        a1 += ((float)t0[1] + (float)t1[1]) + ((float)t2[1] + (float)t3[1]);
        a2 += ((float)t0[2] + (float)t1[2]) + ((float)t2[2] + (float)t3[2]);
        a3 += ((float)t0[3] + (float)t1[3]) + ((float)t2[3] + (float)t3[3]);
    }
    for (; i < end; ++i) {
        half4v t = f[(size_t)eidx[i] * RS + coff];
        a0 += (float)t[0];
        a1 += (float)t[1];
        a2 += (float)t[2];
        a3 += (float)t[3];
    }

    float dv = dinv[v];
    half4v o;
    o[0] = (_Float16)(a0 * dv);
    o[1] = (_Float16)(a1 * dv);
    o[2] = (_Float16)(a2 * dv);
    o[3] = (_Float16)(a3 * dv);
    q[(size_t)v * RS + coff] = o;
}

// ---------------- fp16 MFMA GEMM: A-frags in regs, Wt staged in LDS ----------------
// Block: 64 rows x 256 cols (4 col-chunks of 64). A row-major [NPAD,K] f16,
// Wt row-major [256,K] f16. A is read exactly once per block (all K in regs).
// FUSE1: out f16 = dinv[row]*relu(D+bias); else fp32 out = D+bias.
template <int K, bool FUSE1>
__global__ __launch_bounds__(256) void gemm_mfma(
    const _Float16* __restrict__ A, const _Float16* __restrict__ Wt,
    const float* __restrict__ bias, const float* __restrict__ dinv,
    void* __restrict__ outp) {
    constexpr int LSTR = K + 8;                 // halves; pad to spread LDS banks
    __shared__ _Float16 Bs[64 * LSTR];          // K=256: 33 KB, K=128: 17 KB

    const int tid = threadIdx.x;
    const int wave = tid >> 6;
    const int lane = tid & 63;
    const int m = lane & 15;
    const int quad = lane >> 4;
    const int rbase = blockIdx.x * 64 + wave * 16;
    const int row = rbase + m;

    // All A-fragments for this lane's row, whole K: independent global loads.
    half8 af[K / 32];
    {
        const half8* Arow = (const half8*)(A + (size_t)row * K);
#pragma unroll
        for (int i = 0; i < K / 32; ++i) af[i] = Arow[i * 4 + quad];
    }

    for (int cc = 0; cc < 4; ++cc) {
        const int colbase = cc * 64;
        if (cc) __syncthreads();
        // stage Wt rows [colbase, colbase+64) into LDS (16 B per thread per unit)
        {
            int col = tid >> 2;
            int sub = tid & 3;
            const half8* srcb = (const half8*)(Wt + (size_t)(colbase + col) * K);
            half8* dstb = (half8*)&Bs[col * LSTR];
#pragma unroll
            for (int u = 0; u < K / 32; ++u) dstb[sub + u * 4] = srcb[sub + u * 4];
        }
        __syncthreads();

        float4v acc[4] = {};
#pragma unroll
        for (int k0 = 0; k0 < K; k0 += 32) {
            half8 a = af[k0 >> 5];
#pragma unroll
            for (int c = 0; c < 4; ++c) {
                half8 b = *(const half8*)&Bs[(c * 16 + m) * LSTR + k0 + quad * 8];
                acc[c] = __builtin_amdgcn_mfma_f32_16x16x32_f16(a, b, acc[c], 0, 0, 0);
            }
        }

#pragma unroll
        for (int c = 0; c < 4; ++c) {
            int col = colbase + c * 16 + m;
            float bcol = bias[col];
#pragma unroll
            for (int r = 0; r < 4; ++r) {
                int orow = rbase + quad * 4 + r;   // C/D: col=lane&15, row=quad*4+reg
                if (orow < N) {
                    float val = acc[c][r] + bcol;
                    if (FUSE1) {
                        val = fmaxf(val, 0.f) * dinv[orow];
                        ((_Float16*)outp)[(size_t)orow * 256 + col] = (_Float16)val;
                    } else {
                        ((float*)outp)[(size_t)orow * 256 + col] = val;
                    }
                }
            }
        }
    }
}

extern "C" void kernel_launch(void* const* d_in, const int* in_sizes, int n_in,
                              void* d_out, int out_size, void* d_ws, size_t ws_size,
                              hipStream_t stream) {
    const float* x  = (const float*)d_in[0];
    const int* edge = (const int*)d_in[1];
    const int* src  = edge;
    const int* dst  = edge + E;
    const float* W1 = (const float*)d_in[2];
    const float* b1 = (const float*)d_in[3];
    const float* W2 = (const float*)d_in[4];
    const float* b2 = (const float*)d_in[5];
    float* out = (float*)d_out;

    _Float16* bufA = (_Float16*)d_ws;
    _Float16* bufB = bufA + (size_t)NPAD * 256;
    float* dinv    = (float*)(bufB + (size_t)NPAD * 256);
    int* degI      = (int*)(dinv + N);
    int* rowptr    = degI + N;
    int* cursor    = rowptr + (N + 1);
    int* eidx      = cursor + N;
    _Float16* W1t  = (_Float16*)(eidx + E);
    _Float16* W2t  = W1t + 256 * 128;
    int* blockSums = (int*)(W2t + 256 * 256);

    // ---- CSR + normalization ----
    hipMemsetAsync(degI, 0, N * sizeof(int), stream);
    deg_kernel<<<(E + 255) / 256, 256, 0, stream>>>(dst, degI);
    dinv_kernel<<<(N + 255) / 256, 256, 0, stream>>>(degI, dinv);
    scan1_kernel<<<NB, 256, 0, stream>>>(degI, cursor, blockSums);
    scan2_kernel<<<1, 256, 0, stream>>>(blockSums);
    scan3_kernel<<<NB, 256, 0, stream>>>(degI, cursor, blockSums, rowptr, cursor);
    fill_kernel<<<(E + 255) / 256, 256, 0, stream>>>(src, dst, cursor, eidx);

    // ---- weights to f16 transposed ----
    wt_kernel<128><<<(256 * 128) / 256, 256, 0, stream>>>(W1, W1t);
    wt_kernel<256><<<(256 * 256) / 256, 256, 0, stream>>>(W2, W2t);

    // ---- layer 1:  q1 = Ahat x (aggregate first), h1p = dinv*relu(q1@W1+b1) ----
    prescale_kernel<<<(N * 32 + 255) / 256, 256, 0, stream>>>(
        (const float4*)x, dinv, (half4v*)bufA);
    // 4 chunks x 2 node-segments -> 8 slots; blocks per slot cover N/2 nodes
    aggregate_chunked<128><<<8 * ((N / 2 + 31) / 32), 256, 0, stream>>>(
        rowptr, eidx, (const half4v*)bufA, dinv, (half4v*)bufB);
    gemm_mfma<128, true><<<NPAD / 64, 256, 0, stream>>>(
        bufB, W1t, b1, dinv, bufA);

    // ---- layer 2:  q2 = Ahat h1, out = q2@W2 + b2 ----
    // 8 chunks x 1 segment; blocks per slot cover all N nodes
    aggregate_chunked<256><<<8 * ((N + 31) / 32), 256, 0, stream>>>(
        rowptr, eidx, (const half4v*)bufA, dinv, (half4v*)bufB);
    gemm_mfma<256, false><<<NPAD / 64, 256, 0, stream>>>(
        bufB, W2t, b2, dinv, out);
}

// Round 4
// 323.533 us; speedup vs baseline: 1.0924x; 1.0924x over previous
//
#include <hip/hip_runtime.h>

constexpr int N = 50000;    // nodes
constexpr int E = 800000;   // edges
constexpr int NPAD = 50048; // padded to 64-row multiple for GEMM A tiles
constexpr int NB = (N + 255) / 256;   // 196 scan blocks

typedef _Float16 half8 __attribute__((ext_vector_type(8)));
typedef _Float16 half4v __attribute__((ext_vector_type(4)));
typedef float float4v __attribute__((ext_vector_type(4)));

// ---------------- degree / normalization / CSR ----------------
__global__ __launch_bounds__(256) void deg_kernel(const int* __restrict__ dst,
                                                  int* __restrict__ degI) {
    int e = blockIdx.x * 256 + threadIdx.x;
    if (e < E) atomicAdd(&degI[dst[e]], 1);
}

__global__ __launch_bounds__(256) void dinv_kernel(const int* __restrict__ degI,
                                                   float* __restrict__ dinv) {
    int v = blockIdx.x * 256 + threadIdx.x;
    if (v < N) dinv[v] = rsqrtf((float)degI[v] + 1.0f);   // +1 = self loop
}

// ---- 3-phase scan ----
__global__ __launch_bounds__(256) void scan1_kernel(const int* __restrict__ degI,
                                                    int* __restrict__ incl,
                                                    int* __restrict__ blockSums) {
    __shared__ int s[256];
    int t = threadIdx.x;
    int i = blockIdx.x * 256 + t;
    int d = (i < N) ? degI[i] : 0;
    s[t] = d;
    __syncthreads();
    for (int off = 1; off < 256; off <<= 1) {
        int v = s[t];
        int u = (t >= off) ? s[t - off] : 0;
        __syncthreads();
        s[t] = v + u;
        __syncthreads();
    }
    if (i < N) incl[i] = s[t];
    if (t == 255) blockSums[blockIdx.x] = s[255];
}

__global__ __launch_bounds__(256) void scan2_kernel(int* __restrict__ blockSums) {
    __shared__ int s[256];
    int t = threadIdx.x;
    int v = (t < NB) ? blockSums[t] : 0;
    s[t] = v;
    __syncthreads();
    for (int off = 1; off < 256; off <<= 1) {
        int a = s[t];
        int u = (t >= off) ? s[t - off] : 0;
        __syncthreads();
        s[t] = a + u;
        __syncthreads();
    }
    if (t < NB) blockSums[t] = s[t] - v;   // exclusive block offset
}

__global__ __launch_bounds__(256) void scan3_kernel(const int* __restrict__ degI,
                                                    const int* __restrict__ incl,
                                                    const int* __restrict__ blockSums,
                                                    int* __restrict__ rowptr,
                                                    int* __restrict__ cursor) {
    int i = blockIdx.x * 256 + threadIdx.x;
    if (i < N) {
        int e = blockSums[blockIdx.x] + incl[i] - degI[i];
        rowptr[i] = e;
        cursor[i] = e;
    }
    if (i == 0) rowptr[N] = E;
}

__global__ __launch_bounds__(256) void fill_kernel(const int* __restrict__ src,
                                                   const int* __restrict__ dst,
                                                   int* __restrict__ cursor,
                                                   int* __restrict__ eidx) {
    int e = blockIdx.x * 256 + threadIdx.x;
    if (e >= E) return;
    int d = dst[e];
    int pos = atomicAdd(&cursor[d], 1);
    eidx[pos] = src[e];
}

// ---------------- weight transpose+cast: Wt[n][k] = (f16) W[k][n] ----------------
template <int K>
__global__ __launch_bounds__(256) void wt_kernel(const float* __restrict__ W,
                                                 _Float16* __restrict__ Wt) {
    int idx = blockIdx.x * 256 + threadIdx.x;
    int k = idx & (K - 1);
    int n = idx >> (K == 128 ? 7 : 8);
    Wt[idx] = (_Float16)W[(size_t)k * 256 + n];
}

// ---------------- prescale: px = dinv[v] * x   (fp32 -> fp16, 128 ch) ----------------
__global__ __launch_bounds__(256) void prescale_kernel(const float4* __restrict__ x,
                                                       const float* __restrict__ dinv,
                                                       half4v* __restrict__ px) {
    int idx = blockIdx.x * 256 + threadIdx.x;
    if (idx >= N * 32) return;
    float dv = dinv[idx >> 5];
    float4 t = x[idx];
    half4v o;
    o[0] = (_Float16)(t.x * dv);
    o[1] = (_Float16)(t.y * dv);
    o[2] = (_Float16)(t.z * dv);
    o[3] = (_Float16)(t.w * dv);
    px[idx] = o;
}

// ---------------- wide gather-aggregate: 16 B/lane, 8-edge MLP unroll ----------
// T = channels (256 or 128). half8 loads: 16 B/lane = coalescing sweet spot;
// LPN = T/8 lanes cover a row, so a wave holds 2 (T=256) or 4 (T=128) nodes.
// 8 independent 16 B loads in flight per lane (8 KB/wave). f32 accumulation,
// final *dinv[v], f16 store. VGPR ~60 -> still 8 waves/SIMD.
template <int T>
__global__ __launch_bounds__(256) void aggregate_wide(
    const int* __restrict__ rowptr, const int* __restrict__ eidx,
    const half8* __restrict__ f, const float* __restrict__ dinv,
    half8* __restrict__ q) {
    constexpr int LPN = T / 8;        // lanes per node (32 or 16)
    constexpr int NPB = 256 / LPN;    // nodes per block (8 or 16)

    const int v = blockIdx.x * NPB + threadIdx.x / LPN;
    if (v >= N) return;
    const int lane = threadIdx.x % LPN;
    const size_t base = (size_t)v * LPN + lane;

    // self loop contribution
    half8 s = f[base];
    float a[8];
#pragma unroll
    for (int j = 0; j < 8; ++j) a[j] = (float)s[j];

    int i = rowptr[v];
    const int end = rowptr[v + 1];
    for (; i + 8 <= end; i += 8) {
        int e0 = eidx[i + 0], e1 = eidx[i + 1], e2 = eidx[i + 2], e3 = eidx[i + 3];
        int e4 = eidx[i + 4], e5 = eidx[i + 5], e6 = eidx[i + 6], e7 = eidx[i + 7];
        half8 t0 = f[(size_t)e0 * LPN + lane];
        half8 t1 = f[(size_t)e1 * LPN + lane];
        half8 t2 = f[(size_t)e2 * LPN + lane];
        half8 t3 = f[(size_t)e3 * LPN + lane];
        half8 t4 = f[(size_t)e4 * LPN + lane];
        half8 t5 = f[(size_t)e5 * LPN + lane];
        half8 t6 = f[(size_t)e6 * LPN + lane];
        half8 t7 = f[(size_t)e7 * LPN + lane];
#pragma unroll
        for (int j = 0; j < 8; ++j) {
            a[j] += (((float)t0[j] + (float)t1[j]) + ((float)t2[j] + (float)t3[j])) +
                    (((float)t4[j] + (float)t5[j]) + ((float)t6[j] + (float)t7[j]));
        }
    }
    for (; i + 2 <= end; i += 2) {
        int e0 = eidx[i], e1 = eidx[i + 1];
        half8 t0 = f[(size_t)e0 * LPN + lane];
        half8 t1 = f[(size_t)e1 * LPN + lane];
#pragma unroll
        for (int j = 0; j < 8; ++j) a[j] += (float)t0[j] + (float)t1[j];
    }
    if (i < end) {
        half8 t0 = f[(size_t)eidx[i] * LPN + lane];
#pragma unroll
        for (int j = 0; j < 8; ++j) a[j] += (float)t0[j];
    }

    float dv = dinv[v];
    half8 o;
#pragma unroll
    for (int j = 0; j < 8; ++j) o[j] = (_Float16)(a[j] * dv);
    q[base] = o;
}

// ---------------- fp16 MFMA GEMM: A-frags in regs, Wt staged in LDS ----------------
// Block: 64 rows x 256 cols (4 col-chunks of 64). A row-major [NPAD,K] f16,
// Wt row-major [256,K] f16. A is read exactly once per block (all K in regs).
// FUSE1: out f16 = dinv[row]*relu(D+bias); else fp32 out = D+bias.
template <int K, bool FUSE1>
__global__ __launch_bounds__(256) void gemm_mfma(
    const _Float16* __restrict__ A, const _Float16* __restrict__ Wt,
    const float* __restrict__ bias, const float* __restrict__ dinv,
    void* __restrict__ outp) {
    constexpr int LSTR = K + 8;                 // halves; pad to spread LDS banks
    __shared__ _Float16 Bs[64 * LSTR];          // K=256: 33 KB, K=128: 17 KB

    const int tid = threadIdx.x;
    const int wave = tid >> 6;
    const int lane = tid & 63;
    const int m = lane & 15;
    const int quad = lane >> 4;
    const int rbase = blockIdx.x * 64 + wave * 16;
    const int row = rbase + m;

    // All A-fragments for this lane's row, whole K: independent global loads.
    half8 af[K / 32];
    {
        const half8* Arow = (const half8*)(A + (size_t)row * K);
#pragma unroll
        for (int i = 0; i < K / 32; ++i) af[i] = Arow[i * 4 + quad];
    }

    for (int cc = 0; cc < 4; ++cc) {
        const int colbase = cc * 64;
        if (cc) __syncthreads();
        // stage Wt rows [colbase, colbase+64) into LDS (16 B per thread per unit)
        {
            int col = tid >> 2;
            int sub = tid & 3;
            const half8* srcb = (const half8*)(Wt + (size_t)(colbase + col) * K);
            half8* dstb = (half8*)&Bs[col * LSTR];
#pragma unroll
            for (int u = 0; u < K / 32; ++u) dstb[sub + u * 4] = srcb[sub + u * 4];
        }
        __syncthreads();

        float4v acc[4] = {};
#pragma unroll
        for (int k0 = 0; k0 < K; k0 += 32) {
            half8 a = af[k0 >> 5];
#pragma unroll
            for (int c = 0; c < 4; ++c) {
                half8 b = *(const half8*)&Bs[(c * 16 + m) * LSTR + k0 + quad * 8];
                acc[c] = __builtin_amdgcn_mfma_f32_16x16x32_f16(a, b, acc[c], 0, 0, 0);
            }
        }

#pragma unroll
        for (int c = 0; c < 4; ++c) {
            int col = colbase + c * 16 + m;
            float bcol = bias[col];
#pragma unroll
            for (int r = 0; r < 4; ++r) {
                int orow = rbase + quad * 4 + r;   // C/D: col=lane&15, row=quad*4+reg
                if (orow < N) {
                    float val = acc[c][r] + bcol;
                    if (FUSE1) {
                        val = fmaxf(val, 0.f) * dinv[orow];
                        ((_Float16*)outp)[(size_t)orow * 256 + col] = (_Float16)val;
                    } else {
                        ((float*)outp)[(size_t)orow * 256 + col] = val;
                    }
                }
            }
        }
    }
}

extern "C" void kernel_launch(void* const* d_in, const int* in_sizes, int n_in,
                              void* d_out, int out_size, void* d_ws, size_t ws_size,
                              hipStream_t stream) {
    const float* x  = (const float*)d_in[0];
    const int* edge = (const int*)d_in[1];
    const int* src  = edge;
    const int* dst  = edge + E;
    const float* W1 = (const float*)d_in[2];
    const float* b1 = (const float*)d_in[3];
    const float* W2 = (const float*)d_in[4];
    const float* b2 = (const float*)d_in[5];
    float* out = (float*)d_out;

    _Float16* bufA = (_Float16*)d_ws;
    _Float16* bufB = bufA + (size_t)NPAD * 256;
    float* dinv    = (float*)(bufB + (size_t)NPAD * 256);
    int* degI      = (int*)(dinv + N);
    int* rowptr    = degI + N;
    int* cursor    = rowptr + (N + 1);
    int* eidx      = cursor + N;
    _Float16* W1t  = (_Float16*)(eidx + E);
    _Float16* W2t  = W1t + 256 * 128;
    int* blockSums = (int*)(W2t + 256 * 256);

    // ---- CSR + normalization ----
    hipMemsetAsync(degI, 0, N * sizeof(int), stream);
    deg_kernel<<<(E + 255) / 256, 256, 0, stream>>>(dst, degI);
    dinv_kernel<<<(N + 255) / 256, 256, 0, stream>>>(degI, dinv);
    scan1_kernel<<<NB, 256, 0, stream>>>(degI, cursor, blockSums);
    scan2_kernel<<<1, 256, 0, stream>>>(blockSums);
    scan3_kernel<<<NB, 256, 0, stream>>>(degI, cursor, blockSums, rowptr, cursor);
    fill_kernel<<<(E + 255) / 256, 256, 0, stream>>>(src, dst, cursor, eidx);

    // ---- weights to f16 transposed ----
    wt_kernel<128><<<(256 * 128) / 256, 256, 0, stream>>>(W1, W1t);
    wt_kernel<256><<<(256 * 256) / 256, 256, 0, stream>>>(W2, W2t);

    // ---- layer 1:  q1 = Ahat x (aggregate first), h1p = dinv*relu(q1@W1+b1) ----
    prescale_kernel<<<(N * 32 + 255) / 256, 256, 0, stream>>>(
        (const float4*)x, dinv, (half4v*)bufA);
    aggregate_wide<128><<<(N + 15) / 16, 256, 0, stream>>>(
        rowptr, eidx, (const half8*)bufA, dinv, (half8*)bufB);
    gemm_mfma<128, true><<<NPAD / 64, 256, 0, stream>>>(
        bufB, W1t, b1, dinv, bufA);

    // ---- layer 2:  q2 = Ahat h1, out = q2@W2 + b2 ----
    aggregate_wide<256><<<(N + 7) / 8, 256, 0, stream>>>(
        rowptr, eidx, (const half8*)bufA, dinv, (half8*)bufB);
    gemm_mfma<256, false><<<NPAD / 64, 256, 0, stream>>>(
        bufB, W2t, b2, dinv, out);
}